// Round 7
// baseline (513.881 us; speedup 1.0000x reference)
//
#include <hip/hip_runtime.h>
#include <hip/hip_bf16.h>

#define Nn 100
#define Bb 8
#define Hh 256
#define Ee 9900
#define RE 79200   // Bb*Ee
#define RN 800     // Bb*Nn
#define BN_EPS 1e-5f

typedef __attribute__((ext_vector_type(8))) unsigned short ushort8_t;
typedef __attribute__((ext_vector_type(4))) unsigned short ushort4_t;
typedef __attribute__((ext_vector_type(8))) short bf16x8;   // MFMA A/B frag (4 VGPRs)
typedef __attribute__((ext_vector_type(4))) float f32x4;    // MFMA C/D frag

__device__ __forceinline__ float bf2f(unsigned short u){
  return __uint_as_float(((unsigned)u) << 16);
}
__device__ __forceinline__ unsigned short f2bf(float f){
  unsigned u = __float_as_uint(f);
  return (unsigned short)((u + 0x7fffu + ((u >> 16) & 1u)) >> 16);
}

// BN affine via LDS (for mlp3/k_out which are not LDS-constrained)
__device__ __forceinline__ void affine_prologue(const float* __restrict__ stats,
    float cnt, const float* __restrict__ g, const float* __restrict__ beta,
    float* a, float* c, int tid){
  if (tid < 256){
    float inv = 1.0f / cnt;
    float mu  = stats[tid] * inv;
    float var = fmaxf(stats[256 + tid] * inv - mu * mu, 0.f);
    float aa  = g[tid] * rsqrtf(var + BN_EPS);
    a[tid] = aa;
    c[tid] = beta[tid] - mu * aa;
  }
}

// BN affine in registers (4 cols starting at cb)
__device__ __forceinline__ void affine_reg(const float* __restrict__ stats,
    float cnt, const float* __restrict__ g, const float* __restrict__ be,
    int cb, float4& av, float4& cv){
  float4 s = *(const float4*)(stats + cb);
  float4 q = *(const float4*)(stats + 256 + cb);
  float4 gg = *(const float4*)(g + cb);
  float4 bb = *(const float4*)(be + cb);
  float inv = 1.0f / cnt;
  float mx = s.x*inv, my = s.y*inv, mz = s.z*inv, mw = s.w*inv;
  av.x = gg.x * rsqrtf(fmaxf(q.x*inv - mx*mx, 0.f) + BN_EPS); cv.x = bb.x - mx*av.x;
  av.y = gg.y * rsqrtf(fmaxf(q.y*inv - my*my, 0.f) + BN_EPS); cv.y = bb.y - my*av.y;
  av.z = gg.z * rsqrtf(fmaxf(q.z*inv - mz*mz, 0.f) + BN_EPS); cv.z = bb.z - mz*av.z;
  av.w = gg.w * rsqrtf(fmaxf(q.w*inv - mw*mw, 0.f) + BN_EPS); cv.w = bb.w - mw*av.w;
}

// acc[8][4] += IN(32x256 f32 LDS) @ W(256x256 f32 global). thread: tr=tid>>6, tc=tid&63
__device__ __forceinline__ void gemm_f32(const float* IN, const float* __restrict__ W,
                                         float acc[8][4], int tr, int tc){
  for (int k = 0; k < 256; k += 4){
    float4 w0 = *(const float4*)(W + (size_t)(k+0)*256 + 4*tc);
    float4 w1 = *(const float4*)(W + (size_t)(k+1)*256 + 4*tc);
    float4 w2 = *(const float4*)(W + (size_t)(k+2)*256 + 4*tc);
    float4 w3 = *(const float4*)(W + (size_t)(k+3)*256 + 4*tc);
    #pragma unroll
    for (int rr = 0; rr < 8; rr++){
      float4 iv = *(const float4*)(IN + (tr*8+rr)*256 + k);
      acc[rr][0] += iv.x*w0.x + iv.y*w1.x + iv.z*w2.x + iv.w*w3.x;
      acc[rr][1] += iv.x*w0.y + iv.y*w1.y + iv.z*w2.y + iv.w*w3.y;
      acc[rr][2] += iv.x*w0.z + iv.y*w1.z + iv.z*w2.z + iv.w*w3.z;
      acc[rr][3] += iv.x*w0.w + iv.y*w1.w + iv.z*w2.w + iv.w*w3.w;
    }
  }
}

// MFMA GEMM: A = LDS [32][KW] bf16 row-major, XOR-swizzled (byte ^= (row&7)<<4).
// B = fragment-packed bf16 weights (see k_wprep). Wave w owns output cols [w*64, w*64+64).
template<int KW>
__device__ __forceinline__ void mfma_gemm(const unsigned short* Alds,
    const unsigned short* __restrict__ Bf, f32x4 acc[2][4], int w, int lane){
  const int l15 = lane & 15, kg = lane >> 4;
  for (int ks = 0; ks < KW/32; ks++){
    int byte0 = ((l15*KW      + ks*32 + kg*8) * 2) ^ ((l15 & 7) << 4);
    int byte1 = (((16+l15)*KW + ks*32 + kg*8) * 2) ^ ((l15 & 7) << 4);
    bf16x8 a0 = *(const bf16x8*)((const char*)Alds + byte0);
    bf16x8 a1 = *(const bf16x8*)((const char*)Alds + byte1);
    const unsigned short* bp = Bf + ((size_t)(ks*16 + w*4)*64 + lane)*8;
    #pragma unroll
    for (int cf = 0; cf < 4; cf++){
      bf16x8 b = *(const bf16x8*)(bp + cf*64*8);
      acc[0][cf] = __builtin_amdgcn_mfma_f32_16x16x32_bf16(a0, b, acc[0][cf], 0,0,0);
      acc[1][cf] = __builtin_amdgcn_mfma_f32_16x16x32_bf16(a1, b, acc[1][cf], 0,0,0);
    }
  }
}

__device__ __forceinline__ void zero_acc(f32x4 acc[2][4]){
  #pragma unroll
  for (int i = 0; i < 2; i++)
    #pragma unroll
    for (int j = 0; j < 4; j++){
      f32x4 z = {0.f, 0.f, 0.f, 0.f};
      acc[i][j] = z;
    }
}

// stats push helper: red[512] LDS partials -> global stats (256 threads: 2 entries each)
#define STATS_PUSH(statsp)                                   \
  __syncthreads();                                           \
  atomicAdd(&(statsp)[tid], red[tid]);                       \
  atomicAdd(&(statsp)[tid + 256], red[tid + 256]);

// ---------------- weight prep: W f32 [ktiles*32, 256] -> B-fragment bf16 layout ----------------
__global__ void k_wprep(const float* __restrict__ W, unsigned short* __restrict__ out,
                        int ktiles){
  int id = blockIdx.x * 256 + threadIdx.x;
  int total = ktiles * 16 * 64;
  if (id >= total) return;
  int lane = id & 63, tile = id >> 6;
  int tc = tile & 15, tk = tile >> 4;
  int kbase = tk*32 + (lane>>4)*8, col = tc*16 + (lane&15);
  ushort8_t o;
  #pragma unroll
  for (int j = 0; j < 8; j++) o[j] = f2bf(W[(size_t)(kbase+j)*256 + col]);
  *(ushort8_t*)(out + (size_t)id*8) = o;
}

// ---------------- mlp1: [800,256] -> h1 (f32) + stats ----------------
__global__ __launch_bounds__(256,2) void k_mlp1(
    const float* __restrict__ x,
    const float* __restrict__ W1, const float* __restrict__ b1,
    const float* __restrict__ W2, const float* __restrict__ b2,
    float* __restrict__ h1, float* __restrict__ stats){
  __shared__ float IN[32*256];
  __shared__ float O1[32*256];
  __shared__ float red[512];
  int tid = threadIdx.x, tr = tid >> 6, tc = tid & 63;
  int r0 = blockIdx.x * 32;
  #pragma unroll
  for (int j = 0; j < 8; j++){
    int idx = tid*4 + j*1024;
    *(float4*)(IN + idx) = *(const float4*)(x + (size_t)r0*256 + idx);
  }
  red[tid] = 0.f; red[tid + 256] = 0.f;
  __syncthreads();
  float acc[8][4];
  #pragma unroll
  for (int rr = 0; rr < 8; rr++){ acc[rr][0]=acc[rr][1]=acc[rr][2]=acc[rr][3]=0.f; }
  gemm_f32(IN, W1, acc, tr, tc);
  {
    float4 bb = *(const float4*)(b1 + 4*tc);
    #pragma unroll
    for (int rr = 0; rr < 8; rr++){
      float4 o;
      o.x = fmaxf(acc[rr][0]+bb.x, 0.f);
      o.y = fmaxf(acc[rr][1]+bb.y, 0.f);
      o.z = fmaxf(acc[rr][2]+bb.z, 0.f);
      o.w = fmaxf(acc[rr][3]+bb.w, 0.f);
      *(float4*)(O1 + (tr*8+rr)*256 + 4*tc) = o;
    }
  }
  __syncthreads();
  #pragma unroll
  for (int rr = 0; rr < 8; rr++){ acc[rr][0]=acc[rr][1]=acc[rr][2]=acc[rr][3]=0.f; }
  gemm_f32(O1, W2, acc, tr, tc);
  {
    float4 bb = *(const float4*)(b2 + 4*tc);
    float ls0=0,ls1=0,ls2=0,ls3=0,lq0=0,lq1=0,lq2=0,lq3=0;
    #pragma unroll
    for (int rr = 0; rr < 8; rr++){
      float4 v;
      v.x = fmaxf(acc[rr][0]+bb.x, 0.f);
      v.y = fmaxf(acc[rr][1]+bb.y, 0.f);
      v.z = fmaxf(acc[rr][2]+bb.z, 0.f);
      v.w = fmaxf(acc[rr][3]+bb.w, 0.f);
      *(float4*)(h1 + ((size_t)(r0 + tr*8 + rr))*256 + 4*tc) = v;
      ls0+=v.x; lq0+=v.x*v.x; ls1+=v.y; lq1+=v.y*v.y;
      ls2+=v.z; lq2+=v.z*v.z; ls3+=v.w; lq3+=v.w*v.w;
    }
    atomicAdd(&red[4*tc+0], ls0); atomicAdd(&red[4*tc+1], ls1);
    atomicAdd(&red[4*tc+2], ls2); atomicAdd(&red[4*tc+3], ls3);
    atomicAdd(&red[256+4*tc+0], lq0); atomicAdd(&red[256+4*tc+1], lq1);
    atomicAdd(&red[256+4*tc+2], lq2); atomicAdd(&red[256+4*tc+3], lq3);
  }
  STATS_PUSH(stats)
}

// ---------------- nodepq: P/Q = bn(h)[800,256] @ W_top/W_bot (f32) ----------------
// grid 50: blocks 0..24 -> P (W rows 0:256), blocks 25..49 -> Q (W rows 256:512)
__global__ __launch_bounds__(256,2) void k_nodepq(
    const float* __restrict__ hsrc, const float* __restrict__ stats,
    const float* __restrict__ g, const float* __restrict__ be,
    const float* __restrict__ W512,
    float* __restrict__ P, float* __restrict__ Q){
  __shared__ float IN[32*256];
  int tid = threadIdx.x, tr = tid >> 6, tc = tid & 63;
  int part = blockIdx.x / 25;
  int r0 = (blockIdx.x % 25) * 32;
  int cb = (tid*4) & 255;
  float4 av, cv;
  affine_reg(stats, (float)RN, g, be, cb, av, cv);
  #pragma unroll
  for (int j = 0; j < 8; j++){
    int idx = tid*4 + j*1024;
    int row = idx >> 8;
    float4 v = *(const float4*)(hsrc + (size_t)(r0+row)*256 + cb);
    float4 o;
    o.x = v.x*av.x + cv.x; o.y = v.y*av.y + cv.y;
    o.z = v.z*av.z + cv.z; o.w = v.w*av.w + cv.w;
    *(float4*)(IN + idx) = o;
  }
  __syncthreads();
  float acc[8][4];
  #pragma unroll
  for (int rr = 0; rr < 8; rr++){ acc[rr][0]=acc[rr][1]=acc[rr][2]=acc[rr][3]=0.f; }
  gemm_f32(IN, W512 + (size_t)part*65536, acc, tr, tc);
  float* out = part ? Q : P;
  #pragma unroll
  for (int rr = 0; rr < 8; rr++){
    float4 o; o.x=acc[rr][0]; o.y=acc[rr][1]; o.z=acc[rr][2]; o.w=acc[rr][3];
    *(float4*)(out + (size_t)(r0 + tr*8 + rr)*256 + 4*tc) = o;
  }
}

// ---------------- mlp2 (PQ gather-add + single MFMA GEMM): -> h2 (bf16) + stats ----------------
__global__ __launch_bounds__(256,6) void k_mlp2(
    const float* __restrict__ P2, const float* __restrict__ Q2,
    const float* __restrict__ b1,
    const unsigned short* __restrict__ W2f, const float* __restrict__ b2,
    unsigned short* __restrict__ h2, float* __restrict__ stats2){
  __shared__ unsigned short O1[32*256];   // swizzled
  __shared__ float red[512];
  int tid = threadIdx.x, w = tid >> 6, lane = tid & 63;
  int l15 = lane & 15, kg = lane >> 4;
  int r0 = blockIdx.x * 32;
  red[tid] = 0.f; red[tid + 256] = 0.f;
  { // O1 = relu(P2[snd] + Q2[rec] + b1), bf16 swizzled
    int cb = lane * 4;
    float4 bb = *(const float4*)(b1 + cb);
    #pragma unroll
    for (int rr = 0; rr < 8; rr++){
      int rl = w*8+rr, rg = r0 + rl;
      int b = rg / Ee, e = rg - b*Ee;
      int i = e / 99, kk = e - i*99;
      int snd = kk + (kk >= i);
      float4 pv = *(const float4*)(P2 + ((size_t)(b*Nn + snd))*256 + cb);
      float4 qv = *(const float4*)(Q2 + ((size_t)(b*Nn + i))*256 + cb);
      ushort4_t o;
      o[0] = f2bf(fmaxf(pv.x+qv.x+bb.x, 0.f));
      o[1] = f2bf(fmaxf(pv.y+qv.y+bb.y, 0.f));
      o[2] = f2bf(fmaxf(pv.z+qv.z+bb.z, 0.f));
      o[3] = f2bf(fmaxf(pv.w+qv.w+bb.w, 0.f));
      int byte = ((rl*256 + cb)*2) ^ ((rl&7)<<4);
      *(ushort4_t*)((char*)O1 + byte) = o;
    }
  }
  __syncthreads();
  f32x4 acc2[2][4];
  zero_acc(acc2);
  mfma_gemm<256>(O1, W2f, acc2, w, lane);
  { // bias+relu -> h2 + stats
    #pragma unroll
    for (int cf = 0; cf < 4; cf++){
      int col = w*64 + cf*16 + l15;
      float bb = b2[col];
      float ls = 0.f, lq = 0.f;
      #pragma unroll
      for (int rf = 0; rf < 2; rf++){
        #pragma unroll
        for (int r = 0; r < 4; r++){
          int row = rf*16 + kg*4 + r;
          float v = fmaxf(acc2[rf][cf][r] + bb, 0.f);
          h2[(size_t)(r0 + row)*256 + col] = f2bf(v);
          ls += v; lq += v*v;
        }
      }
      atomicAdd(&red[col], ls);
      atomicAdd(&red[256+col], lq);
    }
  }
  STATS_PUSH(stats2)
}

// ---------------- e2n: column-parallel incoming-edge sum, 800 blocks ----------------
__global__ __launch_bounds__(256,4) void k_e2n(
    const unsigned short* __restrict__ h2, float* __restrict__ h3in){
  int m = blockIdx.x;                 // node-row 0..799
  int b = m / Nn, i = m - b*Nn;
  int c = threadIdx.x;                // column 0..255
  const unsigned short* base = h2 + ((size_t)(b*Ee + i*99))*256 + c;
  float s = 0.f;
  #pragma unroll 4
  for (int j = 0; j < 99; j++) s += bf2f(base[(size_t)j*256]);
  h3in[(size_t)m*256 + c] = s;        // raw sum; bn2 affine + /N applied in k_mlp3
}

// ---------------- mlp3: bn2-affine(e2n sums)/N -> [800,256] -> h3 (f32) + stats ----------------
__global__ __launch_bounds__(256,2) void k_mlp3(
    const float* __restrict__ h3in, const float* __restrict__ stats2,
    const float* __restrict__ g2, const float* __restrict__ be2,
    const float* __restrict__ W1, const float* __restrict__ b1,
    const float* __restrict__ W2, const float* __restrict__ b2,
    float* __restrict__ h3, float* __restrict__ stats3){
  __shared__ float IN[32*256];
  __shared__ float O1[32*256];
  __shared__ float red[512];
  __shared__ float ap[256], cp[256];
  int tid = threadIdx.x, tr = tid >> 6, lane = tid & 63, tc = lane;
  int r0 = blockIdx.x * 32;
  affine_prologue(stats2, (float)RE, g2, be2, ap, cp, tid);
  red[tid] = 0.f; red[tid + 256] = 0.f;
  __syncthreads();
  {
    int cb = lane * 4;
    float4 av = *(const float4*)(ap+cb), cv = *(const float4*)(cp+cb);
    #pragma unroll
    for (int rr = 0; rr < 8; rr++){
      int m = r0 + tr*8 + rr;
      float4 s = *(const float4*)(h3in + (size_t)m*256 + cb);
      float4 o;
      o.x = (s.x*av.x + 99.f*cv.x) * 0.01f;
      o.y = (s.y*av.y + 99.f*cv.y) * 0.01f;
      o.z = (s.z*av.z + 99.f*cv.z) * 0.01f;
      o.w = (s.w*av.w + 99.f*cv.w) * 0.01f;
      *(float4*)(IN + (tr*8+rr)*256 + cb) = o;
    }
  }
  __syncthreads();
  float acc[8][4];
  #pragma unroll
  for (int rr = 0; rr < 8; rr++){ acc[rr][0]=acc[rr][1]=acc[rr][2]=acc[rr][3]=0.f; }
  gemm_f32(IN, W1, acc, tr, tc);
  {
    float4 bb = *(const float4*)(b1 + 4*tc);
    #pragma unroll
    for (int rr = 0; rr < 8; rr++){
      float4 o;
      o.x = fmaxf(acc[rr][0]+bb.x, 0.f);
      o.y = fmaxf(acc[rr][1]+bb.y, 0.f);
      o.z = fmaxf(acc[rr][2]+bb.z, 0.f);
      o.w = fmaxf(acc[rr][3]+bb.w, 0.f);
      *(float4*)(O1 + (tr*8+rr)*256 + 4*tc) = o;
    }
  }
  __syncthreads();
  #pragma unroll
  for (int rr = 0; rr < 8; rr++){ acc[rr][0]=acc[rr][1]=acc[rr][2]=acc[rr][3]=0.f; }
  gemm_f32(O1, W2, acc, tr, tc);
  {
    float4 bb = *(const float4*)(b2 + 4*tc);
    float ls0=0,ls1=0,ls2=0,ls3=0,lq0=0,lq1=0,lq2=0,lq3=0;
    #pragma unroll
    for (int rr = 0; rr < 8; rr++){
      float4 v;
      v.x = fmaxf(acc[rr][0]+bb.x, 0.f);
      v.y = fmaxf(acc[rr][1]+bb.y, 0.f);
      v.z = fmaxf(acc[rr][2]+bb.z, 0.f);
      v.w = fmaxf(acc[rr][3]+bb.w, 0.f);
      *(float4*)(h3 + ((size_t)(r0 + tr*8 + rr))*256 + 4*tc) = v;
      ls0+=v.x; lq0+=v.x*v.x; ls1+=v.y; lq1+=v.y*v.y;
      ls2+=v.z; lq2+=v.z*v.z; ls3+=v.w; lq3+=v.w*v.w;
    }
    atomicAdd(&red[4*tc+0], ls0); atomicAdd(&red[4*tc+1], ls1);
    atomicAdd(&red[4*tc+2], ls2); atomicAdd(&red[4*tc+3], ls3);
    atomicAdd(&red[256+4*tc+0], lq0); atomicAdd(&red[256+4*tc+1], lq1);
    atomicAdd(&red[256+4*tc+2], lq2); atomicAdd(&red[256+4*tc+3], lq3);
  }
  STATS_PUSH(stats3)
}

// ---------------- mlp4 (skip-GEMM + PQ epilogue + GEMM2): -> h4 (bf16) + stats ----------------
__global__ __launch_bounds__(256,6) void k_mlp4(
    const unsigned short* __restrict__ h2,
    const float* __restrict__ stats2, const float* __restrict__ g2, const float* __restrict__ be2,
    const float* __restrict__ P4, const float* __restrict__ Q4,
    const float* __restrict__ b1,
    const unsigned short* __restrict__ Wsf,   // frag-packed W1 rows 512:768 (skip part)
    const unsigned short* __restrict__ W2f, const float* __restrict__ b2,
    unsigned short* __restrict__ h4, float* __restrict__ stats4){
  __shared__ unsigned short A[32*256];    // skip operand (swizzled); O1 aliases after GEMM1
  __shared__ float red[512];
  __shared__ int sIdx[32], rIdx[32];
  int tid = threadIdx.x, w = tid >> 6, lane = tid & 63;
  int l15 = lane & 15, kg = lane >> 4;
  int r0 = blockIdx.x * 32;
  red[tid] = 0.f; red[tid + 256] = 0.f;
  if (tid < 32){
    int rg = r0 + tid;
    int b = rg / Ee, e = rg - b*Ee;
    int i = e / 99, kk = e - i*99;
    int snd = kk + (kk >= i);
    sIdx[tid] = (b*Nn + snd)*256;
    rIdx[tid] = (b*Nn + i)*256;
  }
  { // stage A = bn2(h2[row]) swizzled bf16
    int cb = lane * 4;
    float4 av, cv;
    affine_reg(stats2, (float)RE, g2, be2, cb, av, cv);
    #pragma unroll
    for (int rr = 0; rr < 8; rr++){
      int rl = w*8+rr, rg = r0 + rl;
      ushort4_t hv = *(const ushort4_t*)(h2 + (size_t)rg*256 + cb);
      ushort4_t o;
      o[0]=f2bf(bf2f(hv[0])*av.x+cv.x);
      o[1]=f2bf(bf2f(hv[1])*av.y+cv.y);
      o[2]=f2bf(bf2f(hv[2])*av.z+cv.z);
      o[3]=f2bf(bf2f(hv[3])*av.w+cv.w);
      int byte = ((rl*256 + cb)*2) ^ ((rl&7)<<4);
      *(ushort4_t*)((char*)A + byte) = o;
    }
  }
  __syncthreads();
  f32x4 acc[2][4];
  zero_acc(acc);
  mfma_gemm<256>(A, Wsf, acc, w, lane);       // skip-part GEMM
  __syncthreads();               // all waves done reading A before O1 overwrites it
  unsigned short* O1 = A;
  { // epilogue1: acc + P4[snd]+Q4[rec] + b1 -> relu -> O1 (swizzled)
    #pragma unroll
    for (int cf = 0; cf < 4; cf++){
      int col = w*64 + cf*16 + l15;
      float bb = b1[col];
      #pragma unroll
      for (int rf = 0; rf < 2; rf++){
        #pragma unroll
        for (int r = 0; r < 4; r++){
          int row = rf*16 + kg*4 + r;
          float v = acc[rf][cf][r] + P4[sIdx[row] + col] + Q4[rIdx[row] + col] + bb;
          v = fmaxf(v, 0.f);
          int byte = ((row*256 + col)*2) ^ ((row&7)<<4);
          *(unsigned short*)((char*)O1 + byte) = f2bf(v);
        }
      }
    }
  }
  __syncthreads();
  f32x4 acc2[2][4];
  zero_acc(acc2);
  mfma_gemm<256>(O1, W2f, acc2, w, lane);
  { // epilogue2: bias+relu -> h4 + stats
    #pragma unroll
    for (int cf = 0; cf < 4; cf++){
      int col = w*64 + cf*16 + l15;
      float bb = b2[col];
      float ls = 0.f, lq = 0.f;
      #pragma unroll
      for (int rf = 0; rf < 2; rf++){
        #pragma unroll
        for (int r = 0; r < 4; r++){
          int row = rf*16 + kg*4 + r;
          float v = fmaxf(acc2[rf][cf][r] + bb, 0.f);
          h4[(size_t)(r0 + row)*256 + col] = f2bf(v);
          ls += v; lq += v*v;
        }
      }
      atomicAdd(&red[col], ls);
      atomicAdd(&red[256+col], lq);
    }
  }
  STATS_PUSH(stats4)
}

// ---------------- out: bn4(h4) @ fc_w + fc_b -> [79200,4] f32 ----------------
__global__ __launch_bounds__(256,2) void k_out(
    const unsigned short* __restrict__ h4, const float* __restrict__ stats4,
    const float* __restrict__ g4, const float* __restrict__ be4,
    const float* __restrict__ fcw, const float* __restrict__ fcb,
    float* __restrict__ out){
  __shared__ unsigned short T[64*264];   // pad 256->264 to break bank alignment
  __shared__ float a4[256], c4[256], Wl[1024];
  int tid = threadIdx.x;
  affine_prologue(stats4, (float)RE, g4, be4, a4, c4, tid);
  #pragma unroll
  for (int j = 0; j < 4; j++){ int id = tid + j*256; Wl[id] = fcw[id]; }
  int r0 = blockIdx.x * 64;
  #pragma unroll
  for (int j = 0; j < 8; j++){
    int flat = tid + j*256;
    int rl = flat >> 5, cs = (flat & 31) * 8;
    ushort8_t v = {0,0,0,0,0,0,0,0};
    if (r0 + rl < RE) v = *(const ushort8_t*)(h4 + (size_t)(r0+rl)*256 + cs);
    *(ushort8_t*)(&T[rl*264 + cs]) = v;
  }
  __syncthreads();
  int row = tid >> 2, o = tid & 3;
  if (r0 + row < RE){
    float acc = fcb[o];
    for (int k = 0; k < 256; k += 8){
      ushort8_t iv = *(const ushort8_t*)(&T[row*264 + k]);
      #pragma unroll
      for (int kk = 0; kk < 8; kk++){
        float v = bf2f(iv[kk]) * a4[k+kk] + c4[k+kk];
        acc += v * Wl[(k+kk)*4 + o];
      }
    }
    out[(size_t)(r0+row)*4 + o] = acc;
  }
}

extern "C" void kernel_launch(void* const* d_in, const int* in_sizes, int n_in,
                              void* d_out, int out_size, void* d_ws, size_t ws_size,
                              hipStream_t stream){
  const float* x    = (const float*)d_in[0];
  const float* m1w1 = (const float*)d_in[6];  const float* m1b1 = (const float*)d_in[7];
  const float* m1w2 = (const float*)d_in[8];  const float* m1b2 = (const float*)d_in[9];
  const float* m1g  = (const float*)d_in[10]; const float* m1be = (const float*)d_in[11];
  const float* m2w1 = (const float*)d_in[12]; const float* m2b1 = (const float*)d_in[13];
  const float* m2w2 = (const float*)d_in[14]; const float* m2b2 = (const float*)d_in[15];
  const float* m2g  = (const float*)d_in[16]; const float* m2be = (const float*)d_in[17];
  const float* m3w1 = (const float*)d_in[18]; const float* m3b1 = (const float*)d_in[19];
  const float* m3w2 = (const float*)d_in[20]; const float* m3b2 = (const float*)d_in[21];
  const float* m3g  = (const float*)d_in[22]; const float* m3be = (const float*)d_in[23];
  const float* m4w1 = (const float*)d_in[24]; const float* m4b1 = (const float*)d_in[25];
  const float* m4w2 = (const float*)d_in[26]; const float* m4b2 = (const float*)d_in[27];
  const float* m4g  = (const float*)d_in[28]; const float* m4be = (const float*)d_in[29];
  const float* fcw  = (const float*)d_in[30]; const float* fcb  = (const float*)d_in[31];

  // Workspace (f32 words): h1, h3, stats, h3in, P2, Q2, P4, Q4; then bf16 h2, h4, 3 frag-packs
  size_t need_bytes = 1435648ull * 4ull
                    + (2ull * (size_t)RE * 256ull + 3ull * 65536ull) * 2ull;  // ~87 MB
  if (ws_size < need_bytes) return;

  float* ws = (float*)d_ws;
  float* h1   = ws;                      // 800*256
  float* h3   = ws + 204800;             // 800*256
  float* stats= ws + 409600;             // 4 x 512 (sum|sumsq)
  float* h3in = ws + 411648;             // 800*256 (e2n raw sums)
  float* P2   = ws + 616448;             // 800*256
  float* Q2   = ws + 821248;             // 800*256
  float* P4   = ws + 1026048;            // 800*256
  float* Q4   = ws + 1230848;            // 800*256  (end floats: 1435648)
  unsigned short* h2  = (unsigned short*)(ws + 1435648);  // 79200*256 bf16
  unsigned short* h4  = h2 + (size_t)RE * 256;            // 79200*256 bf16
  unsigned short* w2b = h4 + (size_t)RE * 256;            // 8-ktile frag pack (65536)
  unsigned short* w4s = w2b + 65536;                      // 8-ktile frag pack
  unsigned short* w4b = w4s + 65536;                      // 8-ktile frag pack

  hipMemsetAsync(stats, 0, 2048 * sizeof(float), stream);

  k_wprep<<<(8*16*64)/256, 256, 0, stream>>>(m2w2, w2b, 8);
  k_wprep<<<(8*16*64)/256, 256, 0, stream>>>(m4w1 + (size_t)512*256, w4s, 8);
  k_wprep<<<(8*16*64)/256, 256, 0, stream>>>(m4w2, w4b, 8);

  k_mlp1<<<RN/32, 256, 0, stream>>>(x, m1w1, m1b1, m1w2, m1b2, h1, stats);
  k_nodepq<<<50, 256, 0, stream>>>(h1, stats, m1g, m1be, m2w1, P2, Q2);
  k_mlp2<<<RE/32, 256, 0, stream>>>(P2, Q2, m2b1, w2b, m2b2, h2, stats + 512);
  k_e2n<<<RN, 256, 0, stream>>>(h2, h3in);
  k_mlp3<<<RN/32, 256, 0, stream>>>(h3in, stats + 512, m2g, m2be,
                                    m3w1, m3b1, m3w2, m3b2, h3, stats + 1024);
  k_nodepq<<<50, 256, 0, stream>>>(h3, stats + 1024, m3g, m3be, m4w1, P4, Q4);
  k_mlp4<<<RE/32, 256, 0, stream>>>(h2, stats + 512, m2g, m2be,
                                    P4, Q4, m4b1, w4s, w4b, m4b2, h4, stats + 1536);
  k_out<<<(RE+63)/64, 256, 0, stream>>>(h4, stats + 1536, m4g, m4be,
                                        fcw, fcb, (float*)d_out);
}

// Round 8
// 504.731 us; speedup vs baseline: 1.0181x; 1.0181x over previous
//
#include <hip/hip_runtime.h>
#include <hip/hip_bf16.h>

#define Nn 100
#define Bb 8
#define Hh 256
#define Ee 9900
#define RE 79200   // Bb*Ee
#define RN 800     // Bb*Nn
#define BN_EPS 1e-5f

typedef __attribute__((ext_vector_type(8))) unsigned short ushort8_t;
typedef __attribute__((ext_vector_type(4))) unsigned short ushort4_t;
typedef __attribute__((ext_vector_type(8))) short bf16x8;   // MFMA A/B frag (4 VGPRs)
typedef __attribute__((ext_vector_type(4))) float f32x4;    // MFMA C/D frag

__device__ __forceinline__ float bf2f(unsigned short u){
  return __uint_as_float(((unsigned)u) << 16);
}
__device__ __forceinline__ unsigned short f2bf(float f){
  unsigned u = __float_as_uint(f);
  return (unsigned short)((u + 0x7fffu + ((u >> 16) & 1u)) >> 16);
}

// BN affine via LDS (for mlp3/k_out which are not LDS-constrained)
__device__ __forceinline__ void affine_prologue(const float* __restrict__ stats,
    float cnt, const float* __restrict__ g, const float* __restrict__ beta,
    float* a, float* c, int tid){
  if (tid < 256){
    float inv = 1.0f / cnt;
    float mu  = stats[tid] * inv;
    float var = fmaxf(stats[256 + tid] * inv - mu * mu, 0.f);
    float aa  = g[tid] * rsqrtf(var + BN_EPS);
    a[tid] = aa;
    c[tid] = beta[tid] - mu * aa;
  }
}

// BN affine in registers (4 cols starting at cb)
__device__ __forceinline__ void affine_reg(const float* __restrict__ stats,
    float cnt, const float* __restrict__ g, const float* __restrict__ be,
    int cb, float4& av, float4& cv){
  float4 s = *(const float4*)(stats + cb);
  float4 q = *(const float4*)(stats + 256 + cb);
  float4 gg = *(const float4*)(g + cb);
  float4 bb = *(const float4*)(be + cb);
  float inv = 1.0f / cnt;
  float mx = s.x*inv, my = s.y*inv, mz = s.z*inv, mw = s.w*inv;
  av.x = gg.x * rsqrtf(fmaxf(q.x*inv - mx*mx, 0.f) + BN_EPS); cv.x = bb.x - mx*av.x;
  av.y = gg.y * rsqrtf(fmaxf(q.y*inv - my*my, 0.f) + BN_EPS); cv.y = bb.y - my*av.y;
  av.z = gg.z * rsqrtf(fmaxf(q.z*inv - mz*mz, 0.f) + BN_EPS); cv.z = bb.z - mz*av.z;
  av.w = gg.w * rsqrtf(fmaxf(q.w*inv - mw*mw, 0.f) + BN_EPS); cv.w = bb.w - mw*av.w;
}

// acc[8][4] += IN(32x256 f32 LDS) @ W(256x256 f32 global). thread: tr=tid>>6, tc=tid&63
__device__ __forceinline__ void gemm_f32(const float* IN, const float* __restrict__ W,
                                         float acc[8][4], int tr, int tc){
  for (int k = 0; k < 256; k += 4){
    float4 w0 = *(const float4*)(W + (size_t)(k+0)*256 + 4*tc);
    float4 w1 = *(const float4*)(W + (size_t)(k+1)*256 + 4*tc);
    float4 w2 = *(const float4*)(W + (size_t)(k+2)*256 + 4*tc);
    float4 w3 = *(const float4*)(W + (size_t)(k+3)*256 + 4*tc);
    #pragma unroll
    for (int rr = 0; rr < 8; rr++){
      float4 iv = *(const float4*)(IN + (tr*8+rr)*256 + k);
      acc[rr][0] += iv.x*w0.x + iv.y*w1.x + iv.z*w2.x + iv.w*w3.x;
      acc[rr][1] += iv.x*w0.y + iv.y*w1.y + iv.z*w2.y + iv.w*w3.y;
      acc[rr][2] += iv.x*w0.z + iv.y*w1.z + iv.z*w2.z + iv.w*w3.z;
      acc[rr][3] += iv.x*w0.w + iv.y*w1.w + iv.z*w2.w + iv.w*w3.w;
    }
  }
}

// 64-row MFMA GEMM: A = LDS [64][256] bf16 row-major, XOR-swizzled (byte ^= (row&7)<<4).
// B = fragment-packed bf16 weights. Wave w owns cols [w*64, w*64+64), all 64 rows.
__device__ __forceinline__ void mfma_gemm64(const unsigned short* Alds,
    const unsigned short* __restrict__ Bf, f32x4 acc[4][4], int w, int lane){
  const int l15 = lane & 15, kg = lane >> 4;
  for (int ks = 0; ks < 8; ks++){
    bf16x8 a[4];
    #pragma unroll
    for (int rf = 0; rf < 4; rf++){
      int byte = (((rf*16 + l15)*256 + ks*32 + kg*8) * 2) ^ ((l15 & 7) << 4);
      a[rf] = *(const bf16x8*)((const char*)Alds + byte);
    }
    const unsigned short* bp = Bf + ((size_t)(ks*16 + w*4)*64 + lane)*8;
    #pragma unroll
    for (int cf = 0; cf < 4; cf++){
      bf16x8 b = *(const bf16x8*)(bp + cf*64*8);
      #pragma unroll
      for (int rf = 0; rf < 4; rf++)
        acc[rf][cf] = __builtin_amdgcn_mfma_f32_16x16x32_bf16(a[rf], b, acc[rf][cf], 0,0,0);
    }
  }
}

__device__ __forceinline__ void zero_acc4(f32x4 acc[4][4]){
  #pragma unroll
  for (int i = 0; i < 4; i++)
    #pragma unroll
    for (int j = 0; j < 4; j++){
      f32x4 z = {0.f, 0.f, 0.f, 0.f};
      acc[i][j] = z;
    }
}

// stats push helper: red[512] LDS partials -> global stats (256 threads: 2 entries each)
#define STATS_PUSH(statsp)                                   \
  __syncthreads();                                           \
  atomicAdd(&(statsp)[tid], red[tid]);                       \
  atomicAdd(&(statsp)[tid + 256], red[tid + 256]);

// ---------------- weight prep: W f32 [ktiles*32, 256] -> B-fragment bf16 layout ----------------
__global__ void k_wprep(const float* __restrict__ W, unsigned short* __restrict__ out,
                        int ktiles){
  int id = blockIdx.x * 256 + threadIdx.x;
  int total = ktiles * 16 * 64;
  if (id >= total) return;
  int lane = id & 63, tile = id >> 6;
  int tc = tile & 15, tk = tile >> 4;
  int kbase = tk*32 + (lane>>4)*8, col = tc*16 + (lane&15);
  ushort8_t o;
  #pragma unroll
  for (int j = 0; j < 8; j++) o[j] = f2bf(W[(size_t)(kbase+j)*256 + col]);
  *(ushort8_t*)(out + (size_t)id*8) = o;
}

// ---------------- mlp1: [800,256] -> h1 (f32) + stats ----------------
__global__ __launch_bounds__(256,2) void k_mlp1(
    const float* __restrict__ x,
    const float* __restrict__ W1, const float* __restrict__ b1,
    const float* __restrict__ W2, const float* __restrict__ b2,
    float* __restrict__ h1, float* __restrict__ stats){
  __shared__ float IN[32*256];
  __shared__ float O1[32*256];
  __shared__ float red[512];
  int tid = threadIdx.x, tr = tid >> 6, tc = tid & 63;
  int r0 = blockIdx.x * 32;
  #pragma unroll
  for (int j = 0; j < 8; j++){
    int idx = tid*4 + j*1024;
    *(float4*)(IN + idx) = *(const float4*)(x + (size_t)r0*256 + idx);
  }
  red[tid] = 0.f; red[tid + 256] = 0.f;
  __syncthreads();
  float acc[8][4];
  #pragma unroll
  for (int rr = 0; rr < 8; rr++){ acc[rr][0]=acc[rr][1]=acc[rr][2]=acc[rr][3]=0.f; }
  gemm_f32(IN, W1, acc, tr, tc);
  {
    float4 bb = *(const float4*)(b1 + 4*tc);
    #pragma unroll
    for (int rr = 0; rr < 8; rr++){
      float4 o;
      o.x = fmaxf(acc[rr][0]+bb.x, 0.f);
      o.y = fmaxf(acc[rr][1]+bb.y, 0.f);
      o.z = fmaxf(acc[rr][2]+bb.z, 0.f);
      o.w = fmaxf(acc[rr][3]+bb.w, 0.f);
      *(float4*)(O1 + (tr*8+rr)*256 + 4*tc) = o;
    }
  }
  __syncthreads();
  #pragma unroll
  for (int rr = 0; rr < 8; rr++){ acc[rr][0]=acc[rr][1]=acc[rr][2]=acc[rr][3]=0.f; }
  gemm_f32(O1, W2, acc, tr, tc);
  {
    float4 bb = *(const float4*)(b2 + 4*tc);
    float ls0=0,ls1=0,ls2=0,ls3=0,lq0=0,lq1=0,lq2=0,lq3=0;
    #pragma unroll
    for (int rr = 0; rr < 8; rr++){
      float4 v;
      v.x = fmaxf(acc[rr][0]+bb.x, 0.f);
      v.y = fmaxf(acc[rr][1]+bb.y, 0.f);
      v.z = fmaxf(acc[rr][2]+bb.z, 0.f);
      v.w = fmaxf(acc[rr][3]+bb.w, 0.f);
      *(float4*)(h1 + ((size_t)(r0 + tr*8 + rr))*256 + 4*tc) = v;
      ls0+=v.x; lq0+=v.x*v.x; ls1+=v.y; lq1+=v.y*v.y;
      ls2+=v.z; lq2+=v.z*v.z; ls3+=v.w; lq3+=v.w*v.w;
    }
    atomicAdd(&red[4*tc+0], ls0); atomicAdd(&red[4*tc+1], ls1);
    atomicAdd(&red[4*tc+2], ls2); atomicAdd(&red[4*tc+3], ls3);
    atomicAdd(&red[256+4*tc+0], lq0); atomicAdd(&red[256+4*tc+1], lq1);
    atomicAdd(&red[256+4*tc+2], lq2); atomicAdd(&red[256+4*tc+3], lq3);
  }
  STATS_PUSH(stats)
}

// ---------------- nodepq: P/Q = bn(h)[800,256] @ W_top/W_bot -> bf16 ----------------
// grid 50: blocks 0..24 -> P (W rows 0:256), blocks 25..49 -> Q (W rows 256:512)
__global__ __launch_bounds__(256,2) void k_nodepq(
    const float* __restrict__ hsrc, const float* __restrict__ stats,
    const float* __restrict__ g, const float* __restrict__ be,
    const float* __restrict__ W512,
    unsigned short* __restrict__ P, unsigned short* __restrict__ Q){
  __shared__ float IN[32*256];
  int tid = threadIdx.x, tr = tid >> 6, tc = tid & 63;
  int part = blockIdx.x / 25;
  int r0 = (blockIdx.x % 25) * 32;
  int cb = (tid*4) & 255;
  float4 av, cv;
  affine_reg(stats, (float)RN, g, be, cb, av, cv);
  #pragma unroll
  for (int j = 0; j < 8; j++){
    int idx = tid*4 + j*1024;
    int row = idx >> 8;
    float4 v = *(const float4*)(hsrc + (size_t)(r0+row)*256 + cb);
    float4 o;
    o.x = v.x*av.x + cv.x; o.y = v.y*av.y + cv.y;
    o.z = v.z*av.z + cv.z; o.w = v.w*av.w + cv.w;
    *(float4*)(IN + idx) = o;
  }
  __syncthreads();
  float acc[8][4];
  #pragma unroll
  for (int rr = 0; rr < 8; rr++){ acc[rr][0]=acc[rr][1]=acc[rr][2]=acc[rr][3]=0.f; }
  gemm_f32(IN, W512 + (size_t)part*65536, acc, tr, tc);
  unsigned short* out = part ? Q : P;
  #pragma unroll
  for (int rr = 0; rr < 8; rr++){
    ushort4_t o;
    o[0]=f2bf(acc[rr][0]); o[1]=f2bf(acc[rr][1]);
    o[2]=f2bf(acc[rr][2]); o[3]=f2bf(acc[rr][3]);
    *(ushort4_t*)(out + (size_t)(r0 + tr*8 + rr)*256 + 4*tc) = o;
  }
}

// ---------------- mlp2 (64-row blocks): relu(P[snd]+Q[rec]+b1) -> GEMM -> h2 + stats ----------------
__global__ __launch_bounds__(256,4) void k_mlp2(
    const unsigned short* __restrict__ P2, const unsigned short* __restrict__ Q2,
    const float* __restrict__ b1,
    const unsigned short* __restrict__ W2f, const float* __restrict__ b2,
    unsigned short* __restrict__ h2, float* __restrict__ stats2){
  __shared__ unsigned short O1[64*256];   // swizzled
  __shared__ float red[512];
  int tid = threadIdx.x, w = tid >> 6, lane = tid & 63;
  int l15 = lane & 15, kg = lane >> 4;
  int r0 = blockIdx.x * 64;
  red[tid] = 0.f; red[tid + 256] = 0.f;
  { // O1 = relu(P2[snd] + Q2[rec] + b1), bf16 swizzled
    int cb = lane * 4;
    float4 bb = *(const float4*)(b1 + cb);
    #pragma unroll
    for (int rr = 0; rr < 16; rr++){
      int rl = w*16+rr, rg = r0 + rl;
      int rgc = rg < RE ? rg : RE-1;
      int b = rgc / Ee, e = rgc - b*Ee;
      int i = e / 99, kk = e - i*99;
      int snd = kk + (kk >= i);
      ushort4_t pv = *(const ushort4_t*)(P2 + ((size_t)(b*Nn + snd))*256 + cb);
      ushort4_t qv = *(const ushort4_t*)(Q2 + ((size_t)(b*Nn + i))*256 + cb);
      ushort4_t o;
      o[0] = f2bf(fmaxf(bf2f(pv[0])+bf2f(qv[0])+bb.x, 0.f));
      o[1] = f2bf(fmaxf(bf2f(pv[1])+bf2f(qv[1])+bb.y, 0.f));
      o[2] = f2bf(fmaxf(bf2f(pv[2])+bf2f(qv[2])+bb.z, 0.f));
      o[3] = f2bf(fmaxf(bf2f(pv[3])+bf2f(qv[3])+bb.w, 0.f));
      int byte = ((rl*256 + cb)*2) ^ ((rl&7)<<4);
      *(ushort4_t*)((char*)O1 + byte) = o;
    }
  }
  __syncthreads();
  f32x4 acc2[4][4];
  zero_acc4(acc2);
  mfma_gemm64(O1, W2f, acc2, w, lane);
  { // bias+relu -> h2 + stats (guard last partial block)
    #pragma unroll
    for (int cf = 0; cf < 4; cf++){
      int col = w*64 + cf*16 + l15;
      float bb = b2[col];
      float ls = 0.f, lq = 0.f;
      #pragma unroll
      for (int rf = 0; rf < 4; rf++){
        #pragma unroll
        for (int r = 0; r < 4; r++){
          int row = rf*16 + kg*4 + r;
          if (r0 + row < RE){
            float v = fmaxf(acc2[rf][cf][r] + bb, 0.f);
            h2[(size_t)(r0 + row)*256 + col] = f2bf(v);
            ls += v; lq += v*v;
          }
        }
      }
      atomicAdd(&red[col], ls);
      atomicAdd(&red[256+col], lq);
    }
  }
  STATS_PUSH(stats2)
}

// ---------------- e2n: column-parallel incoming-edge sum, 800 blocks ----------------
__global__ __launch_bounds__(256,4) void k_e2n(
    const unsigned short* __restrict__ h2, float* __restrict__ h3in){
  int m = blockIdx.x;                 // node-row 0..799
  int b = m / Nn, i = m - b*Nn;
  int c = threadIdx.x;                // column 0..255
  const unsigned short* base = h2 + ((size_t)(b*Ee + i*99))*256 + c;
  float s = 0.f;
  #pragma unroll 4
  for (int j = 0; j < 99; j++) s += bf2f(base[(size_t)j*256]);
  h3in[(size_t)m*256 + c] = s;        // raw sum; bn2 affine + /N applied in k_mlp3
}

// ---------------- mlp3: bn2-affine(e2n sums)/N -> [800,256] -> h3 (f32) + stats ----------------
__global__ __launch_bounds__(256,2) void k_mlp3(
    const float* __restrict__ h3in, const float* __restrict__ stats2,
    const float* __restrict__ g2, const float* __restrict__ be2,
    const float* __restrict__ W1, const float* __restrict__ b1,
    const float* __restrict__ W2, const float* __restrict__ b2,
    float* __restrict__ h3, float* __restrict__ stats3){
  __shared__ float IN[32*256];
  __shared__ float O1[32*256];
  __shared__ float red[512];
  __shared__ float ap[256], cp[256];
  int tid = threadIdx.x, tr = tid >> 6, lane = tid & 63, tc = lane;
  int r0 = blockIdx.x * 32;
  affine_prologue(stats2, (float)RE, g2, be2, ap, cp, tid);
  red[tid] = 0.f; red[tid + 256] = 0.f;
  __syncthreads();
  {
    int cb = lane * 4;
    float4 av = *(const float4*)(ap+cb), cv = *(const float4*)(cp+cb);
    #pragma unroll
    for (int rr = 0; rr < 8; rr++){
      int m = r0 + tr*8 + rr;
      float4 s = *(const float4*)(h3in + (size_t)m*256 + cb);
      float4 o;
      o.x = (s.x*av.x + 99.f*cv.x) * 0.01f;
      o.y = (s.y*av.y + 99.f*cv.y) * 0.01f;
      o.z = (s.z*av.z + 99.f*cv.z) * 0.01f;
      o.w = (s.w*av.w + 99.f*cv.w) * 0.01f;
      *(float4*)(IN + (tr*8+rr)*256 + cb) = o;
    }
  }
  __syncthreads();
  float acc[8][4];
  #pragma unroll
  for (int rr = 0; rr < 8; rr++){ acc[rr][0]=acc[rr][1]=acc[rr][2]=acc[rr][3]=0.f; }
  gemm_f32(IN, W1, acc, tr, tc);
  {
    float4 bb = *(const float4*)(b1 + 4*tc);
    #pragma unroll
    for (int rr = 0; rr < 8; rr++){
      float4 o;
      o.x = fmaxf(acc[rr][0]+bb.x, 0.f);
      o.y = fmaxf(acc[rr][1]+bb.y, 0.f);
      o.z = fmaxf(acc[rr][2]+bb.z, 0.f);
      o.w = fmaxf(acc[rr][3]+bb.w, 0.f);
      *(float4*)(O1 + (tr*8+rr)*256 + 4*tc) = o;
    }
  }
  __syncthreads();
  #pragma unroll
  for (int rr = 0; rr < 8; rr++){ acc[rr][0]=acc[rr][1]=acc[rr][2]=acc[rr][3]=0.f; }
  gemm_f32(O1, W2, acc, tr, tc);
  {
    float4 bb = *(const float4*)(b2 + 4*tc);
    float ls0=0,ls1=0,ls2=0,ls3=0,lq0=0,lq1=0,lq2=0,lq3=0;
    #pragma unroll
    for (int rr = 0; rr < 8; rr++){
      float4 v;
      v.x = fmaxf(acc[rr][0]+bb.x, 0.f);
      v.y = fmaxf(acc[rr][1]+bb.y, 0.f);
      v.z = fmaxf(acc[rr][2]+bb.z, 0.f);
      v.w = fmaxf(acc[rr][3]+bb.w, 0.f);
      *(float4*)(h3 + ((size_t)(r0 + tr*8 + rr))*256 + 4*tc) = v;
      ls0+=v.x; lq0+=v.x*v.x; ls1+=v.y; lq1+=v.y*v.y;
      ls2+=v.z; lq2+=v.z*v.z; ls3+=v.w; lq3+=v.w*v.w;
    }
    atomicAdd(&red[4*tc+0], ls0); atomicAdd(&red[4*tc+1], ls1);
    atomicAdd(&red[4*tc+2], ls2); atomicAdd(&red[4*tc+3], ls3);
    atomicAdd(&red[256+4*tc+0], lq0); atomicAdd(&red[256+4*tc+1], lq1);
    atomicAdd(&red[256+4*tc+2], lq2); atomicAdd(&red[256+4*tc+3], lq3);
  }
  STATS_PUSH(stats3)
}

// ---------------- mlp4 (64-row blocks): skip-GEMM + PQ epilogue + GEMM2 -> h4 + stats ----------------
__global__ __launch_bounds__(256,4) void k_mlp4(
    const unsigned short* __restrict__ h2,
    const float* __restrict__ stats2, const float* __restrict__ g2, const float* __restrict__ be2,
    const unsigned short* __restrict__ P4, const unsigned short* __restrict__ Q4,
    const float* __restrict__ b1,
    const unsigned short* __restrict__ Wsf,   // frag-packed W1 rows 512:768 (skip part)
    const unsigned short* __restrict__ W2f, const float* __restrict__ b2,
    unsigned short* __restrict__ h4, float* __restrict__ stats4){
  __shared__ unsigned short A[64*256];    // skip operand (swizzled); O1 aliases after GEMM1
  __shared__ float red[512];
  __shared__ int sIdx[64], rIdx[64];
  int tid = threadIdx.x, w = tid >> 6, lane = tid & 63;
  int l15 = lane & 15, kg = lane >> 4;
  int r0 = blockIdx.x * 64;
  red[tid] = 0.f; red[tid + 256] = 0.f;
  if (tid < 64){
    int rg = r0 + tid;
    int rgc = rg < RE ? rg : RE-1;
    int b = rgc / Ee, e = rgc - b*Ee;
    int i = e / 99, kk = e - i*99;
    int snd = kk + (kk >= i);
    sIdx[tid] = (b*Nn + snd)*256;
    rIdx[tid] = (b*Nn + i)*256;
  }
  { // stage A = bn2(h2[row]) swizzled bf16
    int cb = lane * 4;
    float4 av, cv;
    affine_reg(stats2, (float)RE, g2, be2, cb, av, cv);
    #pragma unroll
    for (int rr = 0; rr < 16; rr++){
      int rl = w*16+rr, rg = r0 + rl;
      int rgc = rg < RE ? rg : RE-1;
      ushort4_t hv = *(const ushort4_t*)(h2 + (size_t)rgc*256 + cb);
      ushort4_t o;
      o[0]=f2bf(bf2f(hv[0])*av.x+cv.x);
      o[1]=f2bf(bf2f(hv[1])*av.y+cv.y);
      o[2]=f2bf(bf2f(hv[2])*av.z+cv.z);
      o[3]=f2bf(bf2f(hv[3])*av.w+cv.w);
      int byte = ((rl*256 + cb)*2) ^ ((rl&7)<<4);
      *(ushort4_t*)((char*)A + byte) = o;
    }
  }
  __syncthreads();
  f32x4 acc[4][4];
  zero_acc4(acc);
  mfma_gemm64(A, Wsf, acc, w, lane);          // skip-part GEMM
  __syncthreads();               // all waves done reading A before O1 overwrites it
  unsigned short* O1 = A;
  { // epilogue1: acc + P4[snd]+Q4[rec] + b1 -> relu -> O1 (swizzled)
    #pragma unroll
    for (int cf = 0; cf < 4; cf++){
      int col = w*64 + cf*16 + l15;
      float bb = b1[col];
      #pragma unroll
      for (int rf = 0; rf < 4; rf++){
        #pragma unroll
        for (int r = 0; r < 4; r++){
          int row = rf*16 + kg*4 + r;
          float v = acc[rf][cf][r] + bf2f(P4[sIdx[row] + col]) + bf2f(Q4[rIdx[row] + col]) + bb;
          v = fmaxf(v, 0.f);
          int byte = ((row*256 + col)*2) ^ ((row&7)<<4);
          *(unsigned short*)((char*)O1 + byte) = f2bf(v);
        }
      }
    }
  }
  __syncthreads();
  f32x4 acc2[4][4];
  zero_acc4(acc2);
  mfma_gemm64(O1, W2f, acc2, w, lane);
  { // epilogue2: bias+relu -> h4 + stats (guard last partial block)
    #pragma unroll
    for (int cf = 0; cf < 4; cf++){
      int col = w*64 + cf*16 + l15;
      float bb = b2[col];
      float ls = 0.f, lq = 0.f;
      #pragma unroll
      for (int rf = 0; rf < 4; rf++){
        #pragma unroll
        for (int r = 0; r < 4; r++){
          int row = rf*16 + kg*4 + r;
          if (r0 + row < RE){
            float v = fmaxf(acc2[rf][cf][r] + bb, 0.f);
            h4[(size_t)(r0 + row)*256 + col] = f2bf(v);
            ls += v; lq += v*v;
          }
        }
      }
      atomicAdd(&red[col], ls);
      atomicAdd(&red[256+col], lq);
    }
  }
  STATS_PUSH(stats4)
}

// ---------------- out: bn4(h4) @ fc_w + fc_b -> [79200,4] f32 ----------------
__global__ __launch_bounds__(256,2) void k_out(
    const unsigned short* __restrict__ h4, const float* __restrict__ stats4,
    const float* __restrict__ g4, const float* __restrict__ be4,
    const float* __restrict__ fcw, const float* __restrict__ fcb,
    float* __restrict__ out){
  __shared__ unsigned short T[64*264];   // pad 256->264 to break bank alignment
  __shared__ float a4[256], c4[256], Wl[1024];
  int tid = threadIdx.x;
  affine_prologue(stats4, (float)RE, g4, be4, a4, c4, tid);
  #pragma unroll
  for (int j = 0; j < 4; j++){ int id = tid + j*256; Wl[id] = fcw[id]; }
  int r0 = blockIdx.x * 64;
  #pragma unroll
  for (int j = 0; j < 8; j++){
    int flat = tid + j*256;
    int rl = flat >> 5, cs = (flat & 31) * 8;
    ushort8_t v = {0,0,0,0,0,0,0,0};
    if (r0 + rl < RE) v = *(const ushort8_t*)(h4 + (size_t)(r0+rl)*256 + cs);
    *(ushort8_t*)(&T[rl*264 + cs]) = v;
  }
  __syncthreads();
  int row = tid >> 2, o = tid & 3;
  if (r0 + row < RE){
    float acc = fcb[o];
    for (int k = 0; k < 256; k += 8){
      ushort8_t iv = *(const ushort8_t*)(&T[row*264 + k]);
      #pragma unroll
      for (int kk = 0; kk < 8; kk++){
        float v = bf2f(iv[kk]) * a4[k+kk] + c4[k+kk];
        acc += v * Wl[(k+kk)*4 + o];
      }
    }
    out[(size_t)(r0+row)*4 + o] = acc;
  }
}

extern "C" void kernel_launch(void* const* d_in, const int* in_sizes, int n_in,
                              void* d_out, int out_size, void* d_ws, size_t ws_size,
                              hipStream_t stream){
  const float* x    = (const float*)d_in[0];
  const float* m1w1 = (const float*)d_in[6];  const float* m1b1 = (const float*)d_in[7];
  const float* m1w2 = (const float*)d_in[8];  const float* m1b2 = (const float*)d_in[9];
  const float* m1g  = (const float*)d_in[10]; const float* m1be = (const float*)d_in[11];
  const float* m2w1 = (const float*)d_in[12]; const float* m2b1 = (const float*)d_in[13];
  const float* m2w2 = (const float*)d_in[14]; const float* m2b2 = (const float*)d_in[15];
  const float* m2g  = (const float*)d_in[16]; const float* m2be = (const float*)d_in[17];
  const float* m3w1 = (const float*)d_in[18]; const float* m3b1 = (const float*)d_in[19];
  const float* m3w2 = (const float*)d_in[20]; const float* m3b2 = (const float*)d_in[21];
  const float* m3g  = (const float*)d_in[22]; const float* m3be = (const float*)d_in[23];
  const float* m4w1 = (const float*)d_in[24]; const float* m4b1 = (const float*)d_in[25];
  const float* m4w2 = (const float*)d_in[26]; const float* m4b2 = (const float*)d_in[27];
  const float* m4g  = (const float*)d_in[28]; const float* m4be = (const float*)d_in[29];
  const float* fcw  = (const float*)d_in[30]; const float* fcb  = (const float*)d_in[31];

  // Workspace: f32 region (h1,h3,stats,h3in) then bf16 region (h2,h4,3 frag packs, P2,Q2,P4,Q4)
  size_t need_bytes = 616448ull * 4ull
                    + (2ull * (size_t)RE * 256ull + 3ull * 65536ull + 4ull * 204800ull) * 2ull;
  if (ws_size < need_bytes) return;

  float* ws = (float*)d_ws;
  float* h1   = ws;                      // 800*256
  float* h3   = ws + 204800;             // 800*256
  float* stats= ws + 409600;             // 4 x 512 (sum|sumsq)
  float* h3in = ws + 411648;             // 800*256 (e2n raw sums)
  unsigned short* h2  = (unsigned short*)(ws + 616448);  // 79200*256 bf16
  unsigned short* h4  = h2 + (size_t)RE * 256;            // 79200*256 bf16
  unsigned short* w2b = h4 + (size_t)RE * 256;            // 8-ktile frag pack (65536)
  unsigned short* w4s = w2b + 65536;                      // 8-ktile frag pack
  unsigned short* w4b = w4s + 65536;                      // 8-ktile frag pack
  unsigned short* P2b = w4b + 65536;                      // 800*256 bf16
  unsigned short* Q2b = P2b + 204800;
  unsigned short* P4b = Q2b + 204800;
  unsigned short* Q4b = P4b + 204800;

  hipMemsetAsync(stats, 0, 2048 * sizeof(float), stream);

  k_wprep<<<(8*16*64)/256, 256, 0, stream>>>(m2w2, w2b, 8);
  k_wprep<<<(8*16*64)/256, 256, 0, stream>>>(m4w1 + (size_t)512*256, w4s, 8);
  k_wprep<<<(8*16*64)/256, 256, 0, stream>>>(m4w2, w4b, 8);

  k_mlp1<<<RN/32, 256, 0, stream>>>(x, m1w1, m1b1, m1w2, m1b2, h1, stats);
  k_nodepq<<<50, 256, 0, stream>>>(h1, stats, m1g, m1be, m2w1, P2b, Q2b);
  k_mlp2<<<(RE+63)/64, 256, 0, stream>>>(P2b, Q2b, m2b1, w2b, m2b2, h2, stats + 512);
  k_e2n<<<RN, 256, 0, stream>>>(h2, h3in);
  k_mlp3<<<RN/32, 256, 0, stream>>>(h3in, stats + 512, m2g, m2be,
                                    m3w1, m3b1, m3w2, m3b2, h3, stats + 1024);
  k_nodepq<<<50, 256, 0, stream>>>(h3, stats + 1024, m3g, m3be, m4w1, P4b, Q4b);
  k_mlp4<<<(RE+63)/64, 256, 0, stream>>>(h2, stats + 512, m2g, m2be,
                                         P4b, Q4b, m4b1, w4s, w4b, m4b2, h4, stats + 1536);
  k_out<<<(RE+63)/64, 256, 0, stream>>>(h4, stats + 1536, m4g, m4be,
                                        fcw, fcb, (float*)d_out);
}